// Round 1
// baseline (255.248 us; speedup 1.0000x reference)
//
#include <hip/hip_runtime.h>

// Problem: B=32, H=512, W=512, C=4 float32.
//   m00 = max(0.001, sum(mk)); m10 = sum((x-256)*mk); m01 = sum((y-256)*mk)
//   d = round_half_even(m10/m00, m01/m00)  per batch (int)
//   out[b,i,j,c] = x[b, i+dy, j+dx, c] if in range else 0   (zero pad, NOT clamp)

#define RB 32          // reduction blocks per batch
#define NB 32          // batches
#define HPIX 512
#define WPIX 512
#define PIX_PER_BATCH (HPIX * WPIX)       // 262144
#define PPT 4                              // pixels (float4) per thread in shift
#define PIX_PER_BLOCK (256 * PPT)          // 1024

typedef float f32x4 __attribute__((ext_vector_type(4)));

// ---------------- kernel 1: per-batch partial moments ----------------
// grid = NB*RB blocks x 256 threads. Each block reduces 2048 float4 (8192 mk
// values = 16 rows) deterministically; writes 3 partial floats.
// (unchanged from prior round: proven absmax==0, ~6-7 us, not the bottleneck)
__global__ __launch_bounds__(256) void moments_kernel(const float* __restrict__ mk,
                                                      float* __restrict__ partials) {
    const int b   = blockIdx.x / RB;
    const int blk = blockIdx.x % RB;
    const int tid = threadIdx.x;

    const float4* mk4 = (const float4*)(mk + (size_t)b * PIX_PER_BATCH);
    float a0 = 0.f, ax = 0.f, ay = 0.f;
    const int base = blk * 2048 + tid;   // float4 index within batch
#pragma unroll
    for (int it = 0; it < 8; ++it) {
        const int q = base + it * 256;       // float4 index
        const float4 v = mk4[q];
        const int p  = q << 2;               // float index within batch
        const int y  = p >> 9;               // row
        const int x0 = p & 511;              // col of v.x
        const float wy = (float)(y - 256);
        const float s  = v.x + v.y + v.z + v.w;
        a0 += s;
        ay += wy * s;
        ax += (float)(x0 - 256) * v.x + (float)(x0 - 255) * v.y +
              (float)(x0 - 254) * v.z + (float)(x0 - 253) * v.w;
    }
    __shared__ float r0[256], rx[256], ry[256];
    r0[tid] = a0; rx[tid] = ax; ry[tid] = ay;
    __syncthreads();
    for (int s = 128; s > 0; s >>= 1) {
        if (tid < s) {
            r0[tid] += r0[tid + s];
            rx[tid] += rx[tid + s];
            ry[tid] += ry[tid + s];
        }
        __syncthreads();
    }
    if (tid == 0) {
        float* pb = partials + (size_t)(b * RB + blk) * 3;
        pb[0] = r0[0]; pb[1] = rx[0]; pb[2] = ry[0];
    }
}

// ---------------- kernel 2: fused finalize + shifted copy ----------------
// Old finalize_kernel folded in: every block derives d[b] from the 96 partial
// floats of its batch (L2-hit reads, ~0.4us aggregate), using the EXACT same
// serial accumulation order as the old single-block finalize so the rounded
// integer shift is bit-identical. Removes the 1-block finalize launch bubble.
// PPT=4 float4 per thread for deeper load pipelining; nontemporal stores keep
// the 134MB output stream from evicting x lines in L2.
__global__ __launch_bounds__(256) void shift_kernel(const f32x4* __restrict__ x,
                                                    const float* __restrict__ partials,
                                                    f32x4* __restrict__ out) {
    const int tid  = threadIdx.x;
    const int pix0 = blockIdx.x * PIX_PER_BLOCK;   // global pixel index of block start
    const int b    = pix0 >> 18;                   // PIX_PER_BLOCK divides batch => single b

    __shared__ float sp[RB * 3];
    __shared__ int2  sd;
    if (tid < RB * 3) sp[tid] = partials[(size_t)b * RB * 3 + tid];
    __syncthreads();
    if (tid == 0) {
        float s0 = 0.f, sx = 0.f, sy = 0.f;
        for (int i = 0; i < RB; ++i) {           // same order as old finalize
            s0 += sp[3 * i]; sx += sp[3 * i + 1]; sy += sp[3 * i + 2];
        }
        const float m00 = fmaxf(0.001f, s0);
        // jnp.round = round half to even = rintf under default rounding mode
        sd = make_int2((int)rintf(sx / m00), (int)rintf(sy / m00));
    }
    __syncthreads();
    const int2 db = sd;
    const size_t xbase = (size_t)b << 18;

    int idx = pix0 + tid;                          // global pixel (float4) index
#pragma unroll
    for (int k = 0; k < PPT; ++k, idx += 256) {
        const int ij = idx & (PIX_PER_BATCH - 1);
        const int i  = ij >> 9;                    // row
        const int j  = ij & 511;                   // col
        const int sxp = j + db.x;
        const int syp = i + db.y;
        f32x4 v = (f32x4)0.f;
        if ((unsigned)sxp < (unsigned)WPIX && (unsigned)syp < (unsigned)HPIX) {
            v = x[xbase + ((size_t)syp << 9) + sxp];
        }
        __builtin_nontemporal_store(v, &out[idx]);
    }
}

extern "C" void kernel_launch(void* const* d_in, const int* in_sizes, int n_in,
                              void* d_out, int out_size, void* d_ws, size_t ws_size,
                              hipStream_t stream) {
    const float* x  = (const float*)d_in[0];   // [32,512,512,4]
    const float* mk = (const float*)d_in[1];   // [32,512,512,1]
    float* out = (float*)d_out;                // [32,512,512,4]

    float* partials = (float*)d_ws;            // 3*NB*RB floats = 12288 B

    moments_kernel<<<NB * RB, 256, 0, stream>>>(mk, partials);
    shift_kernel<<<(NB * PIX_PER_BATCH) / PIX_PER_BLOCK, 256, 0, stream>>>(
        (const f32x4*)x, partials, (f32x4*)out);
}

// Round 2
// 251.931 us; speedup vs baseline: 1.0132x; 1.0132x over previous
//
#include <hip/hip_runtime.h>

// Problem: B=32, H=512, W=512, C=4 float32.
//   m00 = max(0.001, sum(mk)); m10 = sum((x-256)*mk); m01 = sum((y-256)*mk)
//   d = round_half_even(m10/m00, m01/m00)  per batch (int)
//   out[b,i,j,c] = x[b, i+dy, j+dx, c] if in range else 0   (zero pad, NOT clamp)

#define RB 32          // reduction blocks per batch
#define NB 32          // batches
#define HPIX 512
#define WPIX 512
#define PIX_PER_BATCH (HPIX * WPIX)       // 262144
#define PPT 8                              // pixels (float4) per thread in shift
#define PIX_PER_BLOCK (256 * PPT)          // 2048

typedef float f32x4 __attribute__((ext_vector_type(4)));

// ---------------- kernel 1: per-batch partial moments ----------------
// grid = NB*RB blocks x 256 threads. Each block reduces 2048 float4 (8192 mk
// values = 16 rows) deterministically; writes 3 partial floats.
// (unchanged: proven absmax==0, ~7 us, not the bottleneck)
__global__ __launch_bounds__(256) void moments_kernel(const float* __restrict__ mk,
                                                      float* __restrict__ partials) {
    const int b   = blockIdx.x / RB;
    const int blk = blockIdx.x % RB;
    const int tid = threadIdx.x;

    const float4* mk4 = (const float4*)(mk + (size_t)b * PIX_PER_BATCH);
    float a0 = 0.f, ax = 0.f, ay = 0.f;
    const int base = blk * 2048 + tid;   // float4 index within batch
#pragma unroll
    for (int it = 0; it < 8; ++it) {
        const int q = base + it * 256;       // float4 index
        const float4 v = mk4[q];
        const int p  = q << 2;               // float index within batch
        const int y  = p >> 9;               // row
        const int x0 = p & 511;              // col of v.x
        const float wy = (float)(y - 256);
        const float s  = v.x + v.y + v.z + v.w;
        a0 += s;
        ay += wy * s;
        ax += (float)(x0 - 256) * v.x + (float)(x0 - 255) * v.y +
              (float)(x0 - 254) * v.z + (float)(x0 - 253) * v.w;
    }
    __shared__ float r0[256], rx[256], ry[256];
    r0[tid] = a0; rx[tid] = ax; ry[tid] = ay;
    __syncthreads();
    for (int s = 128; s > 0; s >>= 1) {
        if (tid < s) {
            r0[tid] += r0[tid + s];
            rx[tid] += rx[tid + s];
            ry[tid] += ry[tid + s];
        }
        __syncthreads();
    }
    if (tid == 0) {
        float* pb = partials + (size_t)(b * RB + blk) * 3;
        pb[0] = r0[0]; pb[1] = rx[0]; pb[2] = ry[0];
    }
}

// ---------------- kernel 2: fused finalize + shifted copy ----------------
// Finalize fused as a per-block prologue (bit-identical serial order -> same
// rounded integer shift as the reference finalize; absmax stays 0).
// Copy restructured for memory-level parallelism: per thread, compute 8
// clamped addresses + validity predicates, issue 8 independent
// global_load_dwordx4 back-to-back, then cndmask-zero + store. No control
// flow between loads -> 8 loads in flight per thread (~8KB/wave) instead of
// the round-1 load->wait->store serialization that plateaued at 2.4 TB/s.
// Regular (write-back) stores: reverts the round-1 nontemporal experiment.
__global__ __launch_bounds__(256) void shift_kernel(const f32x4* __restrict__ x,
                                                    const float* __restrict__ partials,
                                                    f32x4* __restrict__ out) {
    const int tid  = threadIdx.x;
    const int pix0 = blockIdx.x * PIX_PER_BLOCK;   // global pixel index of block start
    const int b    = pix0 >> 18;                   // PIX_PER_BLOCK divides batch => single b

    __shared__ float sp[RB * 3];
    __shared__ int2  sd;
    if (tid < RB * 3) sp[tid] = partials[(size_t)b * RB * 3 + tid];
    __syncthreads();
    if (tid == 0) {
        float s0 = 0.f, sx = 0.f, sy = 0.f;
        for (int i = 0; i < RB; ++i) {           // same order as original finalize
            s0 += sp[3 * i]; sx += sp[3 * i + 1]; sy += sp[3 * i + 2];
        }
        const float m00 = fmaxf(0.001f, s0);
        // jnp.round = round half to even = rintf under default rounding mode
        sd = make_int2((int)rintf(sx / m00), (int)rintf(sy / m00));
    }
    __syncthreads();
    const int2 db = sd;
    const f32x4* __restrict__ xb = x + ((size_t)b << 18);

    const int ij0 = (pix0 & (PIX_PER_BATCH - 1)) + tid;   // within-batch pixel idx, k=0

    f32x4 v[PPT];
    int   ok[PPT];
    // phase 1: addresses + predicates, then 8 independent loads (clamped addr
    // is always in-bounds; OOB lanes get zeroed after).
#pragma unroll
    for (int k = 0; k < PPT; ++k) {
        const int ij  = ij0 + k * 256;
        const int i   = ij >> 9;                   // row
        const int j   = ij & 511;                  // col
        const int sxp = j + db.x;
        const int syp = i + db.y;
        ok[k] = ((unsigned)sxp < (unsigned)WPIX) && ((unsigned)syp < (unsigned)HPIX);
        const int cx = min(max(sxp, 0), WPIX - 1);
        const int cy = min(max(syp, 0), HPIX - 1);
        v[k] = xb[(cy << 9) + cx];
    }
    // phase 2: select + store (stores drain as their load completes)
#pragma unroll
    for (int k = 0; k < PPT; ++k) {
        if (!ok[k]) v[k] = (f32x4)0.f;
        out[pix0 + tid + k * 256] = v[k];
    }
}

extern "C" void kernel_launch(void* const* d_in, const int* in_sizes, int n_in,
                              void* d_out, int out_size, void* d_ws, size_t ws_size,
                              hipStream_t stream) {
    const float* x  = (const float*)d_in[0];   // [32,512,512,4]
    const float* mk = (const float*)d_in[1];   // [32,512,512,1]
    float* out = (float*)d_out;                // [32,512,512,4]

    float* partials = (float*)d_ws;            // 3*NB*RB floats = 12288 B

    moments_kernel<<<NB * RB, 256, 0, stream>>>(mk, partials);
    shift_kernel<<<(NB * PIX_PER_BATCH) / PIX_PER_BLOCK, 256, 0, stream>>>(
        (const f32x4*)x, partials, (f32x4*)out);
}